// Round 1
// baseline (221.382 us; speedup 1.0000x reference)
//
#include <hip/hip_runtime.h>

// SAModule (PointNet++ SA), fused f32-input kernel. R6:
//  - LDS 64KB -> 48KB (weights staged in 16KB halves, register-prefetched) => 3 blocks/CU
//  - block-cooperative ball-query scan (each point loaded once from L2, tested vs 4 centers)
//  - GEMM1/2 use swapped-operand MFMA => transposed C => packed b64 h-writes (no b16 scatter)

typedef unsigned short u16;
typedef unsigned int u32;
typedef unsigned long long u64;
typedef __bf16 bf16x8 __attribute__((ext_vector_type(8)));
typedef float floatx4 __attribute__((ext_vector_type(4)));

#define PCLOUD 4096
#define DIN    64
#define MCENT  8192
#define KNBR   32
#define CAP    448

// smem map (49152 B): sA = [0,32768) 128 rows x 256B; sW = [32768,49152) 1024 uint4.
// phase A/B overlay inside the sA region (dead before gather writes sA):
#define OFF_LIST  0        // u64[4][CAP] = 14336
#define OFF_HIST  14336    // u32[4][32]  = 512
#define OFF_NBRL  14848    // int[4][32]  = 512
#define OFF_CNT   15360    // int[4] acnt | int[4] cnt2
#define OFF_CEN   15392    // float4[4] centers (x,y,z,|c|^2)
#define OFF_BCL   15456    // int[4] cloud ids

__device__ inline u16 f2bf(float f) {          // RNE, no scrub (inputs finite)
    u32 b = __float_as_uint(f);
    b += 0x7fffu + ((b >> 16) & 1u);
    return (u16)(b >> 16);
}
__device__ inline u32 pk2(float a, float b) { return (u32)f2bf(a) | ((u32)f2bf(b) << 16); }
__device__ inline u64 wave_min_u64(u64 v) {
    #pragma unroll
    for (int off = 32; off; off >>= 1) {
        u64 o = __shfl_xor((unsigned long long)v, off);
        if (o < v) v = o;
    }
    return v;
}
__device__ inline u64 d2key(float d2, int j) {
    u32 u = __float_as_uint(d2);
    u = (u & 0x80000000u) ? ~u : (u | 0x80000000u);   // order-preserving map
    return ((u64)u << 32) | (u32)j;
}
__device__ inline int key_bucket(u64 k) {
    u32 hi = (u32)(k >> 32);
    if (hi < 0x80000000u) return 0;                    // d2 <= -0
    float d2 = __uint_as_float(hi & 0x7fffffffu);
    int b = (int)(d2 * 800.0f);                        // 32 buckets over [0, 0.04]
    return b > 31 ? 31 : b;
}

// ---- prep: weights -> bf16 B-fragment images in ws (exact LDS bit layout) ----
// image g (2048 uint4): chunk[n*16 + (kc^(n&7))] = {bf16 W[kc*8+j][n0+n], j=0..7}
// NOTE: n<64 occupies the first 1024 uint4 of each image => 16KB col-halves are contiguous.
__global__ void prep_kernel(const float* __restrict__ W1, const float* __restrict__ W2,
                            const float* __restrict__ W3, uint4* __restrict__ ws) {
    int t = blockIdx.x * 256 + threadIdx.x;   // 0..8191
    int g = t >> 11, r = t & 2047;
    int n = r >> 4, kc = r & 15;
    const float* W; int rs, n0, krows;
    if (g == 0)      { W = W1; rs = 128; n0 = 0;   krows = 67;  }
    else if (g == 1) { W = W2; rs = 128; n0 = 0;   krows = 128; }
    else if (g == 2) { W = W3; rs = 256; n0 = 0;   krows = 128; }
    else             { W = W3; rs = 256; n0 = 128; krows = 128; }
    u16 e[8];
    #pragma unroll
    for (int j = 0; j < 8; j++) {
        int k = kc * 8 + j;
        e[j] = (k < krows) ? f2bf(W[(size_t)k * rs + n0 + n]) : (u16)0;
    }
    ws[(g << 11) + (n << 4) + (kc ^ (n & 7))] = *(const uint4*)e;
}

// Register-prefetch of one 16KB weight half (WS path); fallback computes at commit.
template <bool WS>
__device__ __forceinline__ void pfW(uint4* pf, const uint4* __restrict__ img, int tid) {
    if constexpr (WS) {
        #pragma unroll
        for (int i = 0; i < 4; i++) pf[i] = img[i * 256 + tid];
    }
}
template <bool WS>
__device__ __forceinline__ void cmW(const uint4* pf, uint4* __restrict__ sW4, int tid,
                                    const float* __restrict__ W, int rs, int n0, int krows) {
    if constexpr (WS) {
        #pragma unroll
        for (int i = 0; i < 4; i++) sW4[i * 256 + tid] = pf[i];
    } else {
        #pragma unroll
        for (int it = 0; it < 4; it++) {
            int q = it * 256 + tid;
            int n = q >> 4, kc = q & 15;
            u16 e[8];
            #pragma unroll
            for (int j = 0; j < 8; j++) {
                int k = kc * 8 + j;
                e[j] = (k < krows) ? f2bf(W[(size_t)k * rs + n0 + n]) : (u16)0;
            }
            sW4[(n << 4) + (kc ^ (n & 7))] = *(const uint4*)e;
        }
    }
}

__device__ __forceinline__ void push_hit(int c, float d2, int j,
                                         int* acnt, u32* hist, u64* lists) {
    int p = atomicAdd(&acnt[c], 1);
    int bkt = (int)(d2 * 800.0f);
    bkt = bkt < 0 ? 0 : (bkt > 31 ? 31 : bkt);
    atomicAdd(&hist[c * 32 + bkt], 1u);
    if (p < CAP) lists[c * CAP + p] = d2key(d2, j);
}

template <bool WS>
__global__ __launch_bounds__(256, 3) void sa_kernel(
    const float* __restrict__ x, const float* __restrict__ pos,
    const int* __restrict__ batch, const int* __restrict__ idx,
    const float* __restrict__ W1, const float* __restrict__ b1,
    const float* __restrict__ W2, const float* __restrict__ b2,
    const float* __restrict__ W3, const float* __restrict__ b3,
    const uint4* __restrict__ ws4, float* __restrict__ out) {
    __shared__ __align__(16) char smem[49152];
    u64*  lists = (u64*)(smem + OFF_LIST);
    u32*  hist  = (u32*)(smem + OFF_HIST);
    int*  nbrl  = (int*)(smem + OFF_NBRL);
    int*  acnt  = (int*)(smem + OFF_CNT);
    int*  cnt2  = (int*)(smem + OFF_CNT + 16);
    float4* cen = (float4*)(smem + OFF_CEN);
    int*  bcls  = (int*)(smem + OFF_BCL);

    int tid = threadIdx.x, w = tid >> 6, l = tid & 63;
    int bid = blockIdx.x;
    int m0 = ((bid & 7) << 10) + ((bid >> 3) << 2);   // XCD-friendly: bid%8 ~ cloud
    int m = m0 + w;
    int ic = idx[m] & (8 * PCLOUD - 1);
    float cx = pos[ic * 3], cy = pos[ic * 3 + 1], cz = pos[ic * 3 + 2];
    float sc = __fadd_rn(__fadd_rn(__fmul_rn(cx, cx), __fmul_rn(cy, cy)), __fmul_rn(cz, cz));
    int bcl = batch[ic] & 7;
    int base = bcl << 12;
    const float R2 = 0.04f;

    if (l == 0) { cen[w] = make_float4(cx, cy, cz, sc); bcls[w] = bcl; }
    if (tid < 128) hist[tid] = 0;
    if (tid < 4) { acnt[tid] = 0; cnt2[tid] = 0; }
    if (l == 1) {
        float* o1 = out + MCENT * 256;
        o1[m * 3] = cx; o1[m * 3 + 1] = cy; o1[m * 3 + 2] = cz;
        (o1 + MCENT * 3)[m] = (float)bcl;
    }
    __syncthreads();

    // ---- phase A: cooperative scan, each point loaded once, tested vs 4 centers ----
    bool uni = (bcls[0] == bcls[1]) && (bcls[1] == bcls[2]) && (bcls[2] == bcls[3]);
    if (uni) {
        float4 cA = cen[0], cB = cen[1], cC = cen[2], cD = cen[3];
        int jb = bcls[0] << 12;
        const float* pb = pos + (size_t)jb * 3;
        #pragma unroll 4
        for (int t = tid; t < PCLOUD; t += 256) {
            float px = pb[t * 3], py = pb[t * 3 + 1], pz = pb[t * 3 + 2];
            float sp = __fadd_rn(__fadd_rn(__fmul_rn(px, px), __fmul_rn(py, py)), __fmul_rn(pz, pz));
            {
                float dt = __fadd_rn(__fadd_rn(__fmul_rn(cA.x, px), __fmul_rn(cA.y, py)), __fmul_rn(cA.z, pz));
                float d2 = __fsub_rn(__fadd_rn(cA.w, sp), __fmul_rn(2.0f, dt));
                if (d2 <= R2) push_hit(0, d2, jb + t, acnt, hist, lists);
            }
            {
                float dt = __fadd_rn(__fadd_rn(__fmul_rn(cB.x, px), __fmul_rn(cB.y, py)), __fmul_rn(cB.z, pz));
                float d2 = __fsub_rn(__fadd_rn(cB.w, sp), __fmul_rn(2.0f, dt));
                if (d2 <= R2) push_hit(1, d2, jb + t, acnt, hist, lists);
            }
            {
                float dt = __fadd_rn(__fadd_rn(__fmul_rn(cC.x, px), __fmul_rn(cC.y, py)), __fmul_rn(cC.z, pz));
                float d2 = __fsub_rn(__fadd_rn(cC.w, sp), __fmul_rn(2.0f, dt));
                if (d2 <= R2) push_hit(2, d2, jb + t, acnt, hist, lists);
            }
            {
                float dt = __fadd_rn(__fadd_rn(__fmul_rn(cD.x, px), __fmul_rn(cD.y, py)), __fmul_rn(cD.z, pz));
                float d2 = __fsub_rn(__fadd_rn(cD.w, sp), __fmul_rn(2.0f, dt));
                if (d2 <= R2) push_hit(3, d2, jb + t, acnt, hist, lists);
            }
        }
    } else {
        // rare mixed-cloud block: per-wave scan of own cloud from global
        for (int t = l; t < PCLOUD; t += 64) {
            int j = base + t;
            float px = pos[j * 3], py = pos[j * 3 + 1], pz = pos[j * 3 + 2];
            float sp = __fadd_rn(__fadd_rn(__fmul_rn(px, px), __fmul_rn(py, py)), __fmul_rn(pz, pz));
            float dt = __fadd_rn(__fadd_rn(__fmul_rn(cx, px), __fmul_rn(cy, py)), __fmul_rn(cz, pz));
            float d2 = __fsub_rn(__fadd_rn(sc, sp), __fmul_rn(2.0f, dt));
            if (d2 <= R2) push_hit(w, d2, j, acnt, hist, lists);
        }
    }
    __syncthreads();   // cross-wave list visibility

    int c = acnt[w];
    int nsel = c < KNBR ? c : KNBR;
    u64* mylist = lists + w * CAP;

    // ---- phase B: select the 32 smallest (d2,idx) keys (set only; order free) ----
    int selj = -1;
    if (c <= KNBR) {
        if (l < c) selj = (int)(u32)mylist[l];
    } else if (c <= CAP) {
        u64 kk[7];
        #pragma unroll
        for (int i = 0; i < 7; i++) kk[i] = (l + i * 64 < c) ? mylist[l + i * 64] : ~0ull;
        int hv = (l < 32) ? (int)hist[w * 32 + l] : 0;
        #pragma unroll
        for (int off = 1; off <= 16; off <<= 1) {   // inclusive scan, lanes 0..31
            int o = __shfl_up(hv, off);
            if (l >= off) hv += o;
        }
        u64 ge = __ballot((l < 32) && (hv >= KNBR));
        int B = __ffsll((unsigned long long)ge) - 1;        // threshold bucket
        int S = (B == 0) ? 0 : __shfl(hv, B - 1);           // count strictly below B
        #pragma unroll
        for (int i = 0; i < 7; i++) {                       // bulk-select below B
            if (kk[i] != ~0ull) {
                int bkt = key_bucket(kk[i]);
                if (bkt < B) { int p = atomicAdd(&cnt2[w], 1); nbrl[w * 32 + p] = (int)(u32)kk[i]; }
                if (bkt != B) kk[i] = ~0ull;                // keep only bucket-B keys
            }
        }
        int need = KNBR - S;                                // expected ~4-12 rounds
        u64 last = 0;
        for (int r = 0; r < need; r++) {
            u64 mn = ~0ull;
            #pragma unroll
            for (int i = 0; i < 7; i++) if (kk[i] > last && kk[i] < mn) mn = kk[i];
            mn = wave_min_u64(mn);
            if (l == 0) nbrl[w * 32 + S + r] = (int)(u32)mn;
            last = mn;
        }
        if (l < KNBR) selj = nbrl[w * 32 + l];
    } else {
        // overflow fallback (never taken for uniform data): streaming 32-round argmin
        u64 last = 0;
        for (int r = 0; r < KNBR; r++) {
            u64 mn = ~0ull;
            for (int t = l; t < PCLOUD; t += 64) {
                int j = base + t;
                float px = pos[j * 3], py = pos[j * 3 + 1], pz = pos[j * 3 + 2];
                float sp = __fadd_rn(__fadd_rn(__fmul_rn(px, px), __fmul_rn(py, py)), __fmul_rn(pz, pz));
                float dt = __fadd_rn(__fadd_rn(__fmul_rn(cx, px), __fmul_rn(cy, py)), __fmul_rn(cz, pz));
                float d2 = __fsub_rn(__fadd_rn(sc, sp), __fmul_rn(2.0f, dt));
                if (d2 <= R2) { u64 kf = d2key(d2, j); if (kf > last && kf < mn) mn = kf; }
            }
            mn = wave_min_u64(mn);
            if (l == r) selj = (int)(u32)mn;
            last = mn;
        }
    }
    __syncthreads();   // lists/hist dead; smem becomes sA | sW

    uint4* sA4 = (uint4*)smem;
    uint4* sW4 = (uint4*)(smem + 32768);
    uint4 pf[4];

    // ---- gather 32 feat rows per wave (XOR 16B-chunk swizzle) + stage W1 half0 ----
    {
        pfW<WS>(pf, ws4, tid);
        int h = l & 1, rl = l >> 1;
        int row = w * 32 + rl;
        int j = __shfl(selj, rl);
        int xv = row & 7;
        uint4* dst = sA4 + row * 16;
        uint4 z; z.x = z.y = z.z = z.w = 0;
        if (j >= 0) {
            const float4* sx = (const float4*)(x + (size_t)j * DIN);
            int c0lo = h ? 6 : 0, c0hi = h ? 8 : 6;
            for (int c0 = c0lo; c0 < c0hi; c0++) {
                float4 f0 = sx[c0 * 2], f1 = sx[c0 * 2 + 1];
                uint4 pv;
                pv.x = pk2(f0.x, f0.y); pv.y = pk2(f0.z, f0.w);
                pv.z = pk2(f1.x, f1.y); pv.w = pk2(f1.z, f1.w);
                dst[c0 ^ xv] = pv;
            }
            if (h == 1) {
                float rx = pos[j * 3] - cx, ry = pos[j * 3 + 1] - cy, rz = pos[j * 3 + 2] - cz;
                uint4 rc; rc.x = pk2(rx, ry); rc.y = (u32)f2bf(rz); rc.z = 0; rc.w = 0;
                dst[8 ^ xv] = rc;
                dst[9 ^ xv] = z; dst[10 ^ xv] = z; dst[11 ^ xv] = z;
            }
        } else {
            int c0lo = h ? 6 : 0, c0hi = h ? 12 : 6;
            for (int c0 = c0lo; c0 < c0hi; c0++) dst[c0 ^ xv] = z;
        }
        cmW<WS>(pf, sW4, tid, W1, 128, 0, 67);
    }
    __syncthreads();

    int m16 = l & 15, quad = l >> 4;
    int r0 = w * 32;
    const floatx4 vzero = {0.f, 0.f, 0.f, 0.f};
    floatx4 acc[2][8];

    // ============ GEMM1: h1 = relu(feat @ W1 + b1), K=96, swapped operands ============
    {
        bf16x8 a1[3][2];
        #pragma unroll
        for (int ki = 0; ki < 3; ki++)
            #pragma unroll
            for (int t = 0; t < 2; t++) {
                int row = r0 + t * 16 + m16;
                a1[ki][t] = __builtin_bit_cast(bf16x8, sA4[row * 16 + ((ki * 4 + quad) ^ (row & 7))]);
            }
        #pragma unroll
        for (int t = 0; t < 2; t++)
            #pragma unroll
            for (int cc = 0; cc < 8; cc++) acc[t][cc] = vzero;
        pfW<WS>(pf, ws4 + 1024, tid);                     // W1 cols 64..127
        #pragma unroll
        for (int ki = 0; ki < 3; ki++) {                  // half 0: cols 0..63
            int cb = ki * 4 + quad;
            #pragma unroll
            for (int cc = 0; cc < 4; cc++) {
                int n = cc * 16 + m16;
                bf16x8 b = __builtin_bit_cast(bf16x8, sW4[n * 16 + (cb ^ (n & 7))]);
                #pragma unroll
                for (int t = 0; t < 2; t++)
                    acc[t][cc] = __builtin_amdgcn_mfma_f32_16x16x32_bf16(b, a1[ki][t], acc[t][cc], 0, 0, 0);
            }
        }
        __syncthreads();
        cmW<WS>(pf, sW4, tid, W1, 128, 64, 67);
        __syncthreads();
        pfW<WS>(pf, ws4 + 2048, tid);                     // W2 cols 0..63
        #pragma unroll
        for (int ki = 0; ki < 3; ki++) {                  // half 1: cols 64..127
            int cb = ki * 4 + quad;
            #pragma unroll
            for (int cc = 0; cc < 4; cc++) {
                int n = cc * 16 + m16;
                bf16x8 b = __builtin_bit_cast(bf16x8, sW4[n * 16 + (cb ^ (n & 7))]);
                #pragma unroll
                for (int t = 0; t < 2; t++)
                    acc[t][4 + cc] = __builtin_amdgcn_mfma_f32_16x16x32_bf16(b, a1[ki][t], acc[t][4 + cc], 0, 0, 0);
            }
        }
        // epilogue: lane holds h1[r0+t*16+m16][cc*16+quad*4+i] -> packed b64 writes
        #pragma unroll
        for (int t = 0; t < 2; t++) {
            int rr = r0 + t * 16 + m16;
            char* rowp = smem + rr * 256;
            #pragma unroll
            for (int cc = 0; cc < 8; cc++) {
                float4 bb = ((const float4*)b1)[cc * 4 + quad];
                uint2 pv;
                pv.x = pk2(fmaxf(acc[t][cc][0] + bb.x, 0.f), fmaxf(acc[t][cc][1] + bb.y, 0.f));
                pv.y = pk2(fmaxf(acc[t][cc][2] + bb.z, 0.f), fmaxf(acc[t][cc][3] + bb.w, 0.f));
                *(uint2*)(rowp + (((cc * 2 + (quad >> 1)) ^ (rr & 7)) << 4) + ((quad & 1) << 3)) = pv;
            }
        }
        __syncthreads();
        cmW<WS>(pf, sW4, tid, W2, 128, 0, 128);
        __syncthreads();
    }

    // ============ GEMM2: h2 = relu(h1 @ W2 + b2), K=128, swapped operands ============
    {
        bf16x8 a2[4][2];
        #pragma unroll
        for (int ki = 0; ki < 4; ki++)
            #pragma unroll
            for (int t = 0; t < 2; t++) {
                int row = r0 + t * 16 + m16;
                a2[ki][t] = __builtin_bit_cast(bf16x8, sA4[row * 16 + ((ki * 4 + quad) ^ (row & 7))]);
            }
        #pragma unroll
        for (int t = 0; t < 2; t++)
            #pragma unroll
            for (int cc = 0; cc < 8; cc++) acc[t][cc] = vzero;
        pfW<WS>(pf, ws4 + 3072, tid);                     // W2 cols 64..127
        #pragma unroll
        for (int ki = 0; ki < 4; ki++) {
            int cb = ki * 4 + quad;
            #pragma unroll
            for (int cc = 0; cc < 4; cc++) {
                int n = cc * 16 + m16;
                bf16x8 b = __builtin_bit_cast(bf16x8, sW4[n * 16 + (cb ^ (n & 7))]);
                #pragma unroll
                for (int t = 0; t < 2; t++)
                    acc[t][cc] = __builtin_amdgcn_mfma_f32_16x16x32_bf16(b, a2[ki][t], acc[t][cc], 0, 0, 0);
            }
        }
        __syncthreads();
        cmW<WS>(pf, sW4, tid, W2, 128, 64, 128);
        __syncthreads();
        pfW<WS>(pf, ws4 + 4096, tid);                     // W3 cols 0..63
        #pragma unroll
        for (int ki = 0; ki < 4; ki++) {
            int cb = ki * 4 + quad;
            #pragma unroll
            for (int cc = 0; cc < 4; cc++) {
                int n = cc * 16 + m16;
                bf16x8 b = __builtin_bit_cast(bf16x8, sW4[n * 16 + (cb ^ (n & 7))]);
                #pragma unroll
                for (int t = 0; t < 2; t++)
                    acc[t][4 + cc] = __builtin_amdgcn_mfma_f32_16x16x32_bf16(b, a2[ki][t], acc[t][4 + cc], 0, 0, 0);
            }
        }
        #pragma unroll
        for (int t = 0; t < 2; t++) {
            int rr = r0 + t * 16 + m16;
            char* rowp = smem + rr * 256;
            #pragma unroll
            for (int cc = 0; cc < 8; cc++) {
                float4 bb = ((const float4*)b2)[cc * 4 + quad];
                uint2 pv;
                pv.x = pk2(fmaxf(acc[t][cc][0] + bb.x, 0.f), fmaxf(acc[t][cc][1] + bb.y, 0.f));
                pv.y = pk2(fmaxf(acc[t][cc][2] + bb.z, 0.f), fmaxf(acc[t][cc][3] + bb.w, 0.f));
                *(uint2*)(rowp + (((cc * 2 + (quad >> 1)) ^ (rr & 7)) << 4) + ((quad & 1) << 3)) = pv;
            }
        }
        __syncthreads();
        cmW<WS>(pf, sW4, tid, W3, 256, 0, 128);
        __syncthreads();
    }

    // ====== GEMM3: out = maxpool(relu(h2 @ W3 + b3)), K=128, N=256 in 4 staged quarters ======
    {
        bf16x8 a3[4][2];
        #pragma unroll
        for (int ki = 0; ki < 4; ki++)
            #pragma unroll
            for (int t = 0; t < 2; t++) {
                int row = r0 + t * 16 + m16;
                a3[ki][t] = __builtin_bit_cast(bf16x8, sA4[row * 16 + ((ki * 4 + quad) ^ (row & 7))]);
            }
        #pragma unroll
        for (int st = 0; st < 4; st++) {
            if (st) {
                __syncthreads();
                cmW<WS>(pf, sW4, tid, W3, 256, st * 64, 128);
                __syncthreads();
            }
            if (st < 3) pfW<WS>(pf, ws4 + 5120 + st * 1024, tid);
            floatx4 acc3[2][4];
            #pragma unroll
            for (int t = 0; t < 2; t++)
                #pragma unroll
                for (int cc = 0; cc < 4; cc++) acc3[t][cc] = vzero;
            #pragma unroll
            for (int ki = 0; ki < 4; ki++) {
                int cb = ki * 4 + quad;
                #pragma unroll
                for (int cc = 0; cc < 4; cc++) {
                    int n = cc * 16 + m16;
                    bf16x8 b = __builtin_bit_cast(bf16x8, sW4[n * 16 + (cb ^ (n & 7))]);
                    #pragma unroll
                    for (int t = 0; t < 2; t++)
                        acc3[t][cc] = __builtin_amdgcn_mfma_f32_16x16x32_bf16(a3[ki][t], b, acc3[t][cc], 0, 0, 0);
                }
            }
            #pragma unroll
            for (int cc = 0; cc < 4; cc++) {
                int col = st * 64 + cc * 16 + m16;
                float bias = b3[col];
                float mv = 0.0f;   // post-ReLU max over >=1 valid nbr is >= 0
                #pragma unroll
                for (int t = 0; t < 2; t++)
                    #pragma unroll
                    for (int i = 0; i < 4; i++) {
                        int k = t * 16 + quad * 4 + i;
                        float v = fmaxf(acc3[t][cc][i] + bias, 0.0f);
                        if (k < nsel) mv = fmaxf(mv, v);
                    }
                mv = fmaxf(mv, __shfl_xor(mv, 16));
                mv = fmaxf(mv, __shfl_xor(mv, 32));
                if (quad == 0) out[(m0 + w) * 256 + col] = mv;
            }
        }
    }
}

extern "C" void kernel_launch(void* const* d_in, const int* in_sizes, int n_in,
                              void* d_out, int out_size, void* d_ws, size_t ws_size,
                              hipStream_t stream) {
    const float* x     = (const float*)d_in[0];
    const float* pos   = (const float*)d_in[1];
    const int*   batch = (const int*)d_in[2];
    const int*   idx   = (const int*)d_in[3];
    const float* W1    = (const float*)d_in[4];
    const float* b1    = (const float*)d_in[5];
    const float* W2    = (const float*)d_in[6];
    const float* b2    = (const float*)d_in[7];
    const float* W3    = (const float*)d_in[8];
    const float* b3    = (const float*)d_in[9];
    float* out = (float*)d_out;
    uint4* ws4 = (uint4*)d_ws;

    if (ws_size >= 131072) {
        hipLaunchKernelGGL(prep_kernel, dim3(32), dim3(256), 0, stream, W1, W2, W3, ws4);
        hipLaunchKernelGGL((sa_kernel<true>), dim3(MCENT / 4), dim3(256), 0, stream,
                           x, pos, batch, idx, W1, b1, W2, b2, W3, b3, ws4, out);
    } else {
        hipLaunchKernelGGL((sa_kernel<false>), dim3(MCENT / 4), dim3(256), 0, stream,
                           x, pos, batch, idx, W1, b1, W2, b2, W3, b3, ws4, out);
    }
}

// Round 2
// 158.065 us; speedup vs baseline: 1.4006x; 1.4006x over previous
//
#include <hip/hip_runtime.h>

// SAModule (PointNet++ SA), fused f32-input kernel. R7:
//  - R6 post-mortem: 60MB scratch-spill writes from pf[4] register-prefetch held across
//    barriers/MFMA phases + serialized 16KB cmW staging windows => 134->155us regression.
//  - R7: weights tiled along N in 4KB (16-col) double-buffered steps. K resident in sA,
//    per-wave private output rows => acc[2] (8 VGPR), staging = 1 uint4/thread with
//    one-step live range (no spill), 1 barrier/step, load issued a full step early.
//  - LDS 40KB => 4 blocks/CU (16 waves). Keeps R6 coop phase-A scan + transposed epilogue.

typedef unsigned short u16;
typedef unsigned int u32;
typedef unsigned long long u64;
typedef __bf16 bf16x8 __attribute__((ext_vector_type(8)));
typedef float floatx4 __attribute__((ext_vector_type(4)));

#define PCLOUD 4096
#define DIN    64
#define MCENT  8192
#define KNBR   32
#define CAP    448

// smem map (40960 B): sA = [0,32768) 128 rows x 256B; sW dbuf = [32768,40960) 2 x 4KB.
// phase A/B overlay inside the sA region (dead before gather writes sA):
#define OFF_LIST  0        // u64[4][CAP] = 14336
#define OFF_HIST  14336    // u32[4][32]  = 512
#define OFF_NBRL  14848    // int[4][32]  = 512
#define OFF_CNT   15360    // int[4] acnt | int[4] cnt2
#define OFF_CEN   15392    // float4[4] centers (x,y,z,|c|^2)
#define OFF_BCL   15456    // int[4] cloud ids

__device__ inline u16 f2bf(float f) {          // RNE, no scrub (inputs finite)
    u32 b = __float_as_uint(f);
    b += 0x7fffu + ((b >> 16) & 1u);
    return (u16)(b >> 16);
}
__device__ inline u32 pk2(float a, float b) { return (u32)f2bf(a) | ((u32)f2bf(b) << 16); }
__device__ inline u64 wave_min_u64(u64 v) {
    #pragma unroll
    for (int off = 32; off; off >>= 1) {
        u64 o = __shfl_xor((unsigned long long)v, off);
        if (o < v) v = o;
    }
    return v;
}
__device__ inline u64 d2key(float d2, int j) {
    u32 u = __float_as_uint(d2);
    u = (u & 0x80000000u) ? ~u : (u | 0x80000000u);   // order-preserving map
    return ((u64)u << 32) | (u32)j;
}
__device__ inline int key_bucket(u64 k) {
    u32 hi = (u32)(k >> 32);
    if (hi < 0x80000000u) return 0;                    // d2 <= -0
    float d2 = __uint_as_float(hi & 0x7fffffffu);
    int b = (int)(d2 * 800.0f);                        // 32 buckets over [0, 0.04]
    return b > 31 ? 31 : b;
}

// ---- prep: weights -> bf16 B-fragment images in ws (exact LDS bit layout) ----
// image g (2048 uint4): chunk[n*16 + (kc^(n&7))] = {bf16 W[kc*8+j][n0+n], j=0..7}
// Layout property: ws is 32 contiguous 4KB "step blocks", one per 16 output cols;
// step s (0..31) = cols [s*16, s*16+16) of [W1 | W2 | W3], verbatim LDS image.
__global__ void prep_kernel(const float* __restrict__ W1, const float* __restrict__ W2,
                            const float* __restrict__ W3, uint4* __restrict__ ws) {
    int t = blockIdx.x * 256 + threadIdx.x;   // 0..8191
    int g = t >> 11, r = t & 2047;
    int n = r >> 4, kc = r & 15;
    const float* W; int rs, n0, krows;
    if (g == 0)      { W = W1; rs = 128; n0 = 0;   krows = 67;  }
    else if (g == 1) { W = W2; rs = 128; n0 = 0;   krows = 128; }
    else if (g == 2) { W = W3; rs = 256; n0 = 0;   krows = 128; }
    else             { W = W3; rs = 256; n0 = 128; krows = 128; }
    u16 e[8];
    #pragma unroll
    for (int j = 0; j < 8; j++) {
        int k = kc * 8 + j;
        e[j] = (k < krows) ? f2bf(W[(size_t)k * rs + n0 + n]) : (u16)0;
    }
    ws[(g << 11) + (n << 4) + (kc ^ (n & 7))] = *(const uint4*)e;
}

// Commit one 4KB weight step into a buffer. WS: linear b128 write of the preloaded reg.
// !WS fallback: compute the bf16 packing on the fly (slower; only without workspace).
template <bool WS>
__device__ __forceinline__ void commitW(int s, uint4 ld, uint4* __restrict__ buf, int tid,
                                        const float* __restrict__ W1,
                                        const float* __restrict__ W2,
                                        const float* __restrict__ W3) {
    if constexpr (WS) {
        buf[tid] = ld;
    } else {
        const float* W; int rs, n0, krows;
        if (s < 8)       { W = W1; rs = 128; n0 = s * 16;        krows = 67;  }
        else if (s < 16) { W = W2; rs = 128; n0 = (s - 8) * 16;  krows = 128; }
        else             { W = W3; rs = 256; n0 = (s - 16) * 16; krows = 128; }
        int n = tid >> 4, kc = tid & 15;
        u16 e[8];
        #pragma unroll
        for (int j = 0; j < 8; j++) {
            int k = kc * 8 + j;
            e[j] = (k < krows) ? f2bf(W[(size_t)k * rs + n0 + n]) : (u16)0;
        }
        buf[(n << 4) + (kc ^ (n & 7))] = *(const uint4*)e;
    }
}

__device__ __forceinline__ void push_hit(int c, float d2, int j,
                                         int* acnt, u32* hist, u64* lists) {
    int p = atomicAdd(&acnt[c], 1);
    int bkt = (int)(d2 * 800.0f);
    bkt = bkt < 0 ? 0 : (bkt > 31 ? 31 : bkt);
    atomicAdd(&hist[c * 32 + bkt], 1u);
    if (p < CAP) lists[c * CAP + p] = d2key(d2, j);
}

template <bool WS>
__global__ __launch_bounds__(256, 4) void sa_kernel(
    const float* __restrict__ x, const float* __restrict__ pos,
    const int* __restrict__ batch, const int* __restrict__ idx,
    const float* __restrict__ W1, const float* __restrict__ b1,
    const float* __restrict__ W2, const float* __restrict__ b2,
    const float* __restrict__ W3, const float* __restrict__ b3,
    const uint4* __restrict__ ws4, float* __restrict__ out) {
    __shared__ __align__(16) char smem[40960];
    u64*  lists = (u64*)(smem + OFF_LIST);
    u32*  hist  = (u32*)(smem + OFF_HIST);
    int*  nbrl  = (int*)(smem + OFF_NBRL);
    int*  acnt  = (int*)(smem + OFF_CNT);
    int*  cnt2  = (int*)(smem + OFF_CNT + 16);
    float4* cen = (float4*)(smem + OFF_CEN);
    int*  bcls  = (int*)(smem + OFF_BCL);

    int tid = threadIdx.x, w = tid >> 6, l = tid & 63;
    int bid = blockIdx.x;
    int m0 = ((bid & 7) << 10) + ((bid >> 3) << 2);   // XCD-friendly: bid%8 ~ cloud
    int m = m0 + w;
    int ic = idx[m] & (8 * PCLOUD - 1);
    float cx = pos[ic * 3], cy = pos[ic * 3 + 1], cz = pos[ic * 3 + 2];
    float sc = __fadd_rn(__fadd_rn(__fmul_rn(cx, cx), __fmul_rn(cy, cy)), __fmul_rn(cz, cz));
    int bcl = batch[ic] & 7;
    int base = bcl << 12;
    const float R2 = 0.04f;

    if (l == 0) { cen[w] = make_float4(cx, cy, cz, sc); bcls[w] = bcl; }
    if (tid < 128) hist[tid] = 0;
    if (tid < 4) { acnt[tid] = 0; cnt2[tid] = 0; }
    if (l == 1) {
        float* o1 = out + MCENT * 256;
        o1[m * 3] = cx; o1[m * 3 + 1] = cy; o1[m * 3 + 2] = cz;
        (o1 + MCENT * 3)[m] = (float)bcl;
    }
    __syncthreads();

    // ---- phase A: cooperative scan, each point loaded once, tested vs 4 centers ----
    bool uni = (bcls[0] == bcls[1]) && (bcls[1] == bcls[2]) && (bcls[2] == bcls[3]);
    if (uni) {
        float4 cA = cen[0], cB = cen[1], cC = cen[2], cD = cen[3];
        int jb = bcls[0] << 12;
        const float* pb = pos + (size_t)jb * 3;
        #pragma unroll 4
        for (int t = tid; t < PCLOUD; t += 256) {
            float px = pb[t * 3], py = pb[t * 3 + 1], pz = pb[t * 3 + 2];
            float sp = __fadd_rn(__fadd_rn(__fmul_rn(px, px), __fmul_rn(py, py)), __fmul_rn(pz, pz));
            {
                float dt = __fadd_rn(__fadd_rn(__fmul_rn(cA.x, px), __fmul_rn(cA.y, py)), __fmul_rn(cA.z, pz));
                float d2 = __fsub_rn(__fadd_rn(cA.w, sp), __fmul_rn(2.0f, dt));
                if (d2 <= R2) push_hit(0, d2, jb + t, acnt, hist, lists);
            }
            {
                float dt = __fadd_rn(__fadd_rn(__fmul_rn(cB.x, px), __fmul_rn(cB.y, py)), __fmul_rn(cB.z, pz));
                float d2 = __fsub_rn(__fadd_rn(cB.w, sp), __fmul_rn(2.0f, dt));
                if (d2 <= R2) push_hit(1, d2, jb + t, acnt, hist, lists);
            }
            {
                float dt = __fadd_rn(__fadd_rn(__fmul_rn(cC.x, px), __fmul_rn(cC.y, py)), __fmul_rn(cC.z, pz));
                float d2 = __fsub_rn(__fadd_rn(cC.w, sp), __fmul_rn(2.0f, dt));
                if (d2 <= R2) push_hit(2, d2, jb + t, acnt, hist, lists);
            }
            {
                float dt = __fadd_rn(__fadd_rn(__fmul_rn(cD.x, px), __fmul_rn(cD.y, py)), __fmul_rn(cD.z, pz));
                float d2 = __fsub_rn(__fadd_rn(cD.w, sp), __fmul_rn(2.0f, dt));
                if (d2 <= R2) push_hit(3, d2, jb + t, acnt, hist, lists);
            }
        }
    } else {
        // rare mixed-cloud block: per-wave scan of own cloud from global
        for (int t = l; t < PCLOUD; t += 64) {
            int j = base + t;
            float px = pos[j * 3], py = pos[j * 3 + 1], pz = pos[j * 3 + 2];
            float sp = __fadd_rn(__fadd_rn(__fmul_rn(px, px), __fmul_rn(py, py)), __fmul_rn(pz, pz));
            float dt = __fadd_rn(__fadd_rn(__fmul_rn(cx, px), __fmul_rn(cy, py)), __fmul_rn(cz, pz));
            float d2 = __fsub_rn(__fadd_rn(sc, sp), __fmul_rn(2.0f, dt));
            if (d2 <= R2) push_hit(w, d2, j, acnt, hist, lists);
        }
    }
    __syncthreads();   // cross-wave list visibility

    int c = acnt[w];
    int nsel = c < KNBR ? c : KNBR;
    u64* mylist = lists + w * CAP;

    // ---- phase B: select the 32 smallest (d2,idx) keys (set only; order free) ----
    int selj = -1;
    if (c <= KNBR) {
        if (l < c) selj = (int)(u32)mylist[l];
    } else if (c <= CAP) {
        u64 kk[7];
        #pragma unroll
        for (int i = 0; i < 7; i++) kk[i] = (l + i * 64 < c) ? mylist[l + i * 64] : ~0ull;
        int hv = (l < 32) ? (int)hist[w * 32 + l] : 0;
        #pragma unroll
        for (int off = 1; off <= 16; off <<= 1) {   // inclusive scan, lanes 0..31
            int o = __shfl_up(hv, off);
            if (l >= off) hv += o;
        }
        u64 ge = __ballot((l < 32) && (hv >= KNBR));
        int B = __ffsll((unsigned long long)ge) - 1;        // threshold bucket
        int S = (B == 0) ? 0 : __shfl(hv, B - 1);           // count strictly below B
        #pragma unroll
        for (int i = 0; i < 7; i++) {                       // bulk-select below B
            if (kk[i] != ~0ull) {
                int bkt = key_bucket(kk[i]);
                if (bkt < B) { int p = atomicAdd(&cnt2[w], 1); nbrl[w * 32 + p] = (int)(u32)kk[i]; }
                if (bkt != B) kk[i] = ~0ull;                // keep only bucket-B keys
            }
        }
        int need = KNBR - S;                                // expected ~4-12 rounds
        u64 last = 0;
        for (int r = 0; r < need; r++) {
            u64 mn = ~0ull;
            #pragma unroll
            for (int i = 0; i < 7; i++) if (kk[i] > last && kk[i] < mn) mn = kk[i];
            mn = wave_min_u64(mn);
            if (l == 0) nbrl[w * 32 + S + r] = (int)(u32)mn;
            last = mn;
        }
        if (l < KNBR) selj = nbrl[w * 32 + l];
    } else {
        // overflow fallback (never taken for uniform data): streaming 32-round argmin
        u64 last = 0;
        for (int r = 0; r < KNBR; r++) {
            u64 mn = ~0ull;
            for (int t = l; t < PCLOUD; t += 64) {
                int j = base + t;
                float px = pos[j * 3], py = pos[j * 3 + 1], pz = pos[j * 3 + 2];
                float sp = __fadd_rn(__fadd_rn(__fmul_rn(px, px), __fmul_rn(py, py)), __fmul_rn(pz, pz));
                float dt = __fadd_rn(__fadd_rn(__fmul_rn(cx, px), __fmul_rn(cy, py)), __fmul_rn(cz, pz));
                float d2 = __fsub_rn(__fadd_rn(sc, sp), __fmul_rn(2.0f, dt));
                if (d2 <= R2) { u64 kf = d2key(d2, j); if (kf > last && kf < mn) mn = kf; }
            }
            mn = wave_min_u64(mn);
            if (l == r) selj = (int)(u32)mn;
            last = mn;
        }
    }
    __syncthreads();   // lists/hist dead; smem becomes sA | sW dbuf

    uint4* sA4  = (uint4*)smem;
    uint4* sWb0 = (uint4*)(smem + 32768);
    uint4* sWb1 = (uint4*)(smem + 36864);

    uint4 ld = {};
    if constexpr (WS) ld = ws4[tid];                       // load step 0

    // ---- gather 32 feat rows per wave (XOR 16B-chunk swizzle); rows are wave-private ----
    {
        int h = l & 1, rl = l >> 1;
        int row = w * 32 + rl;
        int j = __shfl(selj, rl);
        int xv = row & 7;
        uint4* dst = sA4 + row * 16;
        uint4 z; z.x = z.y = z.z = z.w = 0;
        if (j >= 0) {
            const float4* sx = (const float4*)(x + (size_t)j * DIN);
            int c0lo = h ? 6 : 0, c0hi = h ? 8 : 6;
            for (int c0 = c0lo; c0 < c0hi; c0++) {
                float4 f0 = sx[c0 * 2], f1 = sx[c0 * 2 + 1];
                uint4 pv;
                pv.x = pk2(f0.x, f0.y); pv.y = pk2(f0.z, f0.w);
                pv.z = pk2(f1.x, f1.y); pv.w = pk2(f1.z, f1.w);
                dst[c0 ^ xv] = pv;
            }
            if (h == 1) {
                float rx = pos[j * 3] - cx, ry = pos[j * 3 + 1] - cy, rz = pos[j * 3 + 2] - cz;
                uint4 rc; rc.x = pk2(rx, ry); rc.y = (u32)f2bf(rz); rc.z = 0; rc.w = 0;
                dst[8 ^ xv] = rc;
                dst[9 ^ xv] = z; dst[10 ^ xv] = z; dst[11 ^ xv] = z;
            }
        } else {
            int c0lo = h ? 6 : 0, c0hi = h ? 12 : 6;
            for (int c0 = c0lo; c0 < c0hi; c0++) dst[c0 ^ xv] = z;
        }
    }
    commitW<WS>(0, ld, sWb0, tid, W1, W2, W3);
    if constexpr (WS) ld = ws4[256 + tid];                 // load step 1
    __syncthreads();

    int m16 = l & 15, quad = l >> 4;
    int r0 = w * 32;
    const floatx4 vzero = {0.f, 0.f, 0.f, 0.f};

    // ======== GEMM1: h1 = relu(feat @ W1 + b1), K=96, swapped operands, 8 N-steps ========
    {
        bf16x8 a1[3][2];
        #pragma unroll
        for (int ki = 0; ki < 3; ki++)
            #pragma unroll
            for (int t = 0; t < 2; t++) {
                int row = r0 + t * 16 + m16;
                a1[ki][t] = __builtin_bit_cast(bf16x8, sA4[row * 16 + ((ki * 4 + quad) ^ (row & 7))]);
            }
        #pragma unroll 2
        for (int s = 0; s < 8; s++) {
            uint4* buf  = (s & 1) ? sWb1 : sWb0;
            uint4* nbuf = (s & 1) ? sWb0 : sWb1;
            floatx4 acc[2] = {vzero, vzero};
            #pragma unroll
            for (int ki = 0; ki < 3; ki++) {
                bf16x8 b = __builtin_bit_cast(bf16x8, buf[(m16 << 4) + ((ki * 4 + quad) ^ (m16 & 7))]);
                #pragma unroll
                for (int t = 0; t < 2; t++)
                    acc[t] = __builtin_amdgcn_mfma_f32_16x16x32_bf16(b, a1[ki][t], acc[t], 0, 0, 0);
            }
            float4 bb = ((const float4*)b1)[s * 4 + quad];  // cols s*16+quad*4..+3
            #pragma unroll
            for (int t = 0; t < 2; t++) {
                int rr = r0 + t * 16 + m16;
                uint2 pv;
                pv.x = pk2(fmaxf(acc[t][0] + bb.x, 0.f), fmaxf(acc[t][1] + bb.y, 0.f));
                pv.y = pk2(fmaxf(acc[t][2] + bb.z, 0.f), fmaxf(acc[t][3] + bb.w, 0.f));
                *(uint2*)(smem + rr * 256 + (((s * 2 + (quad >> 1)) ^ (rr & 7)) << 4) + ((quad & 1) << 3)) = pv;
            }
            commitW<WS>(s + 1, ld, nbuf, tid, W1, W2, W3);
            if constexpr (WS) ld = ws4[(s + 2) * 256 + tid];
            __syncthreads();
        }
    }

    // ======== GEMM2: h2 = relu(h1 @ W2 + b2), K=128, swapped operands, 8 N-steps ========
    {
        bf16x8 a2[4][2];
        #pragma unroll
        for (int ki = 0; ki < 4; ki++)
            #pragma unroll
            for (int t = 0; t < 2; t++) {
                int row = r0 + t * 16 + m16;
                a2[ki][t] = __builtin_bit_cast(bf16x8, sA4[row * 16 + ((ki * 4 + quad) ^ (row & 7))]);
            }
        #pragma unroll 2
        for (int s = 0; s < 8; s++) {
            uint4* buf  = (s & 1) ? sWb1 : sWb0;
            uint4* nbuf = (s & 1) ? sWb0 : sWb1;
            floatx4 acc[2] = {vzero, vzero};
            #pragma unroll
            for (int ki = 0; ki < 4; ki++) {
                bf16x8 b = __builtin_bit_cast(bf16x8, buf[(m16 << 4) + ((ki * 4 + quad) ^ (m16 & 7))]);
                #pragma unroll
                for (int t = 0; t < 2; t++)
                    acc[t] = __builtin_amdgcn_mfma_f32_16x16x32_bf16(b, a2[ki][t], acc[t], 0, 0, 0);
            }
            float4 bb = ((const float4*)b2)[s * 4 + quad];
            #pragma unroll
            for (int t = 0; t < 2; t++) {
                int rr = r0 + t * 16 + m16;
                uint2 pv;
                pv.x = pk2(fmaxf(acc[t][0] + bb.x, 0.f), fmaxf(acc[t][1] + bb.y, 0.f));
                pv.y = pk2(fmaxf(acc[t][2] + bb.z, 0.f), fmaxf(acc[t][3] + bb.w, 0.f));
                *(uint2*)(smem + rr * 256 + (((s * 2 + (quad >> 1)) ^ (rr & 7)) << 4) + ((quad & 1) << 3)) = pv;
            }
            commitW<WS>(s + 9, ld, nbuf, tid, W1, W2, W3);
            if constexpr (WS) ld = ws4[(s + 10) * 256 + tid];
            __syncthreads();
        }
    }

    // ==== GEMM3: out = maxpool(relu(h2 @ W3 + b3)), K=128, N=256, 16 N-steps ====
    {
        bf16x8 a3[4][2];
        #pragma unroll
        for (int ki = 0; ki < 4; ki++)
            #pragma unroll
            for (int t = 0; t < 2; t++) {
                int row = r0 + t * 16 + m16;
                a3[ki][t] = __builtin_bit_cast(bf16x8, sA4[row * 16 + ((ki * 4 + quad) ^ (row & 7))]);
            }
        #pragma unroll 2
        for (int s = 0; s < 16; s++) {
            uint4* buf  = (s & 1) ? sWb1 : sWb0;
            uint4* nbuf = (s & 1) ? sWb0 : sWb1;
            floatx4 acc[2] = {vzero, vzero};
            #pragma unroll
            for (int ki = 0; ki < 4; ki++) {
                bf16x8 b = __builtin_bit_cast(bf16x8, buf[(m16 << 4) + ((ki * 4 + quad) ^ (m16 & 7))]);
                #pragma unroll
                for (int t = 0; t < 2; t++)
                    acc[t] = __builtin_amdgcn_mfma_f32_16x16x32_bf16(a3[ki][t], b, acc[t], 0, 0, 0);
            }
            int col = s * 16 + m16;
            float bias = b3[col];
            float mv = 0.0f;   // post-ReLU max over >=1 valid nbr is >= 0
            #pragma unroll
            for (int t = 0; t < 2; t++)
                #pragma unroll
                for (int i = 0; i < 4; i++) {
                    int k = t * 16 + quad * 4 + i;
                    float v = fmaxf(acc[t][i] + bias, 0.0f);
                    if (k < nsel) mv = fmaxf(mv, v);
                }
            mv = fmaxf(mv, __shfl_xor(mv, 16));
            mv = fmaxf(mv, __shfl_xor(mv, 32));
            if (quad == 0) out[(m0 + w) * 256 + col] = mv;
            if (s < 15) {
                commitW<WS>(s + 17, ld, nbuf, tid, W1, W2, W3);
                if constexpr (WS) { if (s < 14) ld = ws4[(s + 18) * 256 + tid]; }
                __syncthreads();
            }
        }
    }
}

extern "C" void kernel_launch(void* const* d_in, const int* in_sizes, int n_in,
                              void* d_out, int out_size, void* d_ws, size_t ws_size,
                              hipStream_t stream) {
    const float* x     = (const float*)d_in[0];
    const float* pos   = (const float*)d_in[1];
    const int*   batch = (const int*)d_in[2];
    const int*   idx   = (const int*)d_in[3];
    const float* W1    = (const float*)d_in[4];
    const float* b1    = (const float*)d_in[5];
    const float* W2    = (const float*)d_in[6];
    const float* b2    = (const float*)d_in[7];
    const float* W3    = (const float*)d_in[8];
    const float* b3    = (const float*)d_in[9];
    float* out = (float*)d_out;
    uint4* ws4 = (uint4*)d_ws;

    if (ws_size >= 131072) {
        hipLaunchKernelGGL(prep_kernel, dim3(32), dim3(256), 0, stream, W1, W2, W3, ws4);
        hipLaunchKernelGGL((sa_kernel<true>), dim3(MCENT / 4), dim3(256), 0, stream,
                           x, pos, batch, idx, W1, b1, W2, b2, W3, b3, ws4, out);
    } else {
        hipLaunchKernelGGL((sa_kernel<false>), dim3(MCENT / 4), dim3(256), 0, stream,
                           x, pos, batch, idx, W1, b1, W2, b2, W3, b3, ws4, out);
    }
}

// Round 3
// 152.132 us; speedup vs baseline: 1.4552x; 1.0390x over previous
//
#include <hip/hip_runtime.h>

// SAModule (PointNet++ SA), fused f32-input kernel. R8:
//  - R7 post-mortem: spill fixed (52 VGPR, WRITE 8.3MB), sa=91us. VALUBusy 54% (~49us
//    of issue) is now the critical resource; MFMA is at its 12.9us floor.
//  - R8 cuts VALU instructions:
//    * v_cvt_pk_bf16_f32 (1 inst) replaces manual RNE pack (~10 inst) in gather+epilogues
//    * d2 histogram moved out of the phase-A hit body into phase B (rebuilt per-wave from
//      the candidate list, where key_bucket is computed anyway; same-wave LDS ordering)
//    * phase-A scan loads float4 (3 loads / 4 points) instead of 12 scalar dwords

typedef unsigned short u16;
typedef unsigned int u32;
typedef unsigned long long u64;
typedef __bf16 bf16x8 __attribute__((ext_vector_type(8)));
typedef float floatx4 __attribute__((ext_vector_type(4)));

#define PCLOUD 4096
#define DIN    64
#define MCENT  8192
#define KNBR   32
#define CAP    448

// smem map (40960 B): sA = [0,32768) 128 rows x 256B; sW dbuf = [32768,40960) 2 x 4KB.
// phase A/B overlay inside the sA region (dead before gather writes sA):
#define OFF_LIST  0        // u64[4][CAP] = 14336
#define OFF_HIST  14336    // u32[4][32]  = 512
#define OFF_NBRL  14848    // int[4][32]  = 512
#define OFF_CNT   15360    // int[4] acnt | int[4] cnt2
#define OFF_CEN   15392    // float4[4] centers (x,y,z,|c|^2)
#define OFF_BCL   15456    // int[4] cloud ids

__device__ inline u16 f2bf(float f) {          // RNE, no scrub (inputs finite)
    u32 b = __float_as_uint(f);
    b += 0x7fffu + ((b >> 16) & 1u);
    return (u16)(b >> 16);
}
__device__ inline u32 cvtpk(float a, float b) {  // packed {bf16(a), bf16(b)<<16}, RNE
    u32 r;
    asm("v_cvt_pk_bf16_f32 %0, %1, %2" : "=v"(r) : "v"(a), "v"(b));
    return r;
}
__device__ inline u64 wave_min_u64(u64 v) {
    #pragma unroll
    for (int off = 32; off; off >>= 1) {
        u64 o = __shfl_xor((unsigned long long)v, off);
        if (o < v) v = o;
    }
    return v;
}
__device__ inline u64 d2key(float d2, int j) {
    u32 u = __float_as_uint(d2);
    u = (u & 0x80000000u) ? ~u : (u | 0x80000000u);   // order-preserving map
    return ((u64)u << 32) | (u32)j;
}
__device__ inline int key_bucket(u64 k) {
    u32 hi = (u32)(k >> 32);
    if (hi < 0x80000000u) return 0;                    // d2 <= -0
    float d2 = __uint_as_float(hi & 0x7fffffffu);
    int b = (int)(d2 * 800.0f);                        // 32 buckets over [0, 0.04]
    return b > 31 ? 31 : b;
}

// ---- prep: weights -> bf16 B-fragment images in ws (exact LDS bit layout) ----
// image g (2048 uint4): chunk[n*16 + (kc^(n&7))] = {bf16 W[kc*8+j][n0+n], j=0..7}
// Layout property: ws is 32 contiguous 4KB "step blocks", one per 16 output cols;
// step s (0..31) = cols [s*16, s*16+16) of [W1 | W2 | W3], verbatim LDS image.
__global__ void prep_kernel(const float* __restrict__ W1, const float* __restrict__ W2,
                            const float* __restrict__ W3, uint4* __restrict__ ws) {
    int t = blockIdx.x * 256 + threadIdx.x;   // 0..8191
    int g = t >> 11, r = t & 2047;
    int n = r >> 4, kc = r & 15;
    const float* W; int rs, n0, krows;
    if (g == 0)      { W = W1; rs = 128; n0 = 0;   krows = 67;  }
    else if (g == 1) { W = W2; rs = 128; n0 = 0;   krows = 128; }
    else if (g == 2) { W = W3; rs = 256; n0 = 0;   krows = 128; }
    else             { W = W3; rs = 256; n0 = 128; krows = 128; }
    u16 e[8];
    #pragma unroll
    for (int j = 0; j < 8; j++) {
        int k = kc * 8 + j;
        e[j] = (k < krows) ? f2bf(W[(size_t)k * rs + n0 + n]) : (u16)0;
    }
    ws[(g << 11) + (n << 4) + (kc ^ (n & 7))] = *(const uint4*)e;
}

// Commit one 4KB weight step into a buffer. WS: linear b128 write of the preloaded reg.
// !WS fallback: compute the bf16 packing on the fly (slower; only without workspace).
template <bool WS>
__device__ __forceinline__ void commitW(int s, uint4 ld, uint4* __restrict__ buf, int tid,
                                        const float* __restrict__ W1,
                                        const float* __restrict__ W2,
                                        const float* __restrict__ W3) {
    if constexpr (WS) {
        buf[tid] = ld;
    } else {
        const float* W; int rs, n0, krows;
        if (s < 8)       { W = W1; rs = 128; n0 = s * 16;        krows = 67;  }
        else if (s < 16) { W = W2; rs = 128; n0 = (s - 8) * 16;  krows = 128; }
        else             { W = W3; rs = 256; n0 = (s - 16) * 16; krows = 128; }
        int n = tid >> 4, kc = tid & 15;
        u16 e[8];
        #pragma unroll
        for (int j = 0; j < 8; j++) {
            int k = kc * 8 + j;
            e[j] = (k < krows) ? f2bf(W[(size_t)k * rs + n0 + n]) : (u16)0;
        }
        buf[(n << 4) + (kc ^ (n & 7))] = *(const uint4*)e;
    }
}

__device__ __forceinline__ void push_hit(int c, float d2, int j,
                                         int* acnt, u64* lists) {
    int p = atomicAdd(&acnt[c], 1);
    if (p < CAP) lists[c * CAP + p] = d2key(d2, j);
}

template <bool WS>
__global__ __launch_bounds__(256, 4) void sa_kernel(
    const float* __restrict__ x, const float* __restrict__ pos,
    const int* __restrict__ batch, const int* __restrict__ idx,
    const float* __restrict__ W1, const float* __restrict__ b1,
    const float* __restrict__ W2, const float* __restrict__ b2,
    const float* __restrict__ W3, const float* __restrict__ b3,
    const uint4* __restrict__ ws4, float* __restrict__ out) {
    __shared__ __align__(16) char smem[40960];
    u64*  lists = (u64*)(smem + OFF_LIST);
    u32*  hist  = (u32*)(smem + OFF_HIST);
    int*  nbrl  = (int*)(smem + OFF_NBRL);
    int*  acnt  = (int*)(smem + OFF_CNT);
    int*  cnt2  = (int*)(smem + OFF_CNT + 16);
    float4* cen = (float4*)(smem + OFF_CEN);
    int*  bcls  = (int*)(smem + OFF_BCL);

    int tid = threadIdx.x, w = tid >> 6, l = tid & 63;
    int bid = blockIdx.x;
    int m0 = ((bid & 7) << 10) + ((bid >> 3) << 2);   // XCD-friendly: bid%8 ~ cloud
    int m = m0 + w;
    int ic = idx[m] & (8 * PCLOUD - 1);
    float cx = pos[ic * 3], cy = pos[ic * 3 + 1], cz = pos[ic * 3 + 2];
    float sc = __fadd_rn(__fadd_rn(__fmul_rn(cx, cx), __fmul_rn(cy, cy)), __fmul_rn(cz, cz));
    int bcl = batch[ic] & 7;
    int base = bcl << 12;
    const float R2 = 0.04f;

    if (l == 0) { cen[w] = make_float4(cx, cy, cz, sc); bcls[w] = bcl; }
    if (tid < 4) { acnt[tid] = 0; cnt2[tid] = 0; }
    if (l == 1) {
        float* o1 = out + MCENT * 256;
        o1[m * 3] = cx; o1[m * 3 + 1] = cy; o1[m * 3 + 2] = cz;
        (o1 + MCENT * 3)[m] = (float)bcl;
    }
    __syncthreads();

    // ---- phase A: cooperative scan, float4 loads, each point tested vs 4 centers ----
    bool uni = (bcls[0] == bcls[1]) && (bcls[1] == bcls[2]) && (bcls[2] == bcls[3]);
    if (uni) {
        float4 cA = cen[0], cB = cen[1], cC = cen[2], cD = cen[3];
        int jb = bcls[0] << 12;
        const float4* pb4 = (const float4*)(pos + (size_t)jb * 3);

#define TEST1(CEN, CI, SP, PX, PY, PZ, J) { \
    float dt = __fadd_rn(__fadd_rn(__fmul_rn(CEN.x, PX), __fmul_rn(CEN.y, PY)), __fmul_rn(CEN.z, PZ)); \
    float d2 = __fsub_rn(__fadd_rn(CEN.w, SP), __fmul_rn(2.0f, dt)); \
    if (d2 <= R2) push_hit(CI, d2, J, acnt, lists); }
#define TESTP(PX, PY, PZ, J) { \
    float sp = __fadd_rn(__fadd_rn(__fmul_rn(PX, PX), __fmul_rn(PY, PY)), __fmul_rn(PZ, PZ)); \
    TEST1(cA, 0, sp, PX, PY, PZ, J) \
    TEST1(cB, 1, sp, PX, PY, PZ, J) \
    TEST1(cC, 2, sp, PX, PY, PZ, J) \
    TEST1(cD, 3, sp, PX, PY, PZ, J) }

        #pragma unroll
        for (int it = 0; it < 4; it++) {
            int tq = it * 256 + tid;                   // quad-point index 0..1023
            float4 q0 = pb4[tq * 3], q1 = pb4[tq * 3 + 1], q2 = pb4[tq * 3 + 2];
            int j0 = jb + tq * 4;
            TESTP(q0.x, q0.y, q0.z, j0)
            TESTP(q0.w, q1.x, q1.y, j0 + 1)
            TESTP(q1.z, q1.w, q2.x, j0 + 2)
            TESTP(q2.y, q2.z, q2.w, j0 + 3)
        }
#undef TESTP
#undef TEST1
    } else {
        // rare mixed-cloud block: per-wave scan of own cloud from global
        for (int t = l; t < PCLOUD; t += 64) {
            int j = base + t;
            float px = pos[j * 3], py = pos[j * 3 + 1], pz = pos[j * 3 + 2];
            float sp = __fadd_rn(__fadd_rn(__fmul_rn(px, px), __fmul_rn(py, py)), __fmul_rn(pz, pz));
            float dt = __fadd_rn(__fadd_rn(__fmul_rn(cx, px), __fmul_rn(cy, py)), __fmul_rn(cz, pz));
            float d2 = __fsub_rn(__fadd_rn(sc, sp), __fmul_rn(2.0f, dt));
            if (d2 <= R2) push_hit(w, d2, j, acnt, lists);
        }
    }
    __syncthreads();   // cross-wave list visibility

    int c = acnt[w];
    int nsel = c < KNBR ? c : KNBR;
    u64* mylist = lists + w * CAP;

    // ---- phase B: select the 32 smallest (d2,idx) keys (set only; order free) ----
    int selj = -1;
    if (c <= KNBR) {
        if (l < c) selj = (int)(u32)mylist[l];
    } else if (c <= CAP) {
        u64 kk[7];
        int bk[7];
        if (l < 32) hist[w * 32 + l] = 0;              // same-wave LDS: ordered
        #pragma unroll
        for (int i = 0; i < 7; i++) kk[i] = (l + i * 64 < c) ? mylist[l + i * 64] : ~0ull;
        #pragma unroll
        for (int i = 0; i < 7; i++) {                  // build d2 histogram (this wave only)
            bk[i] = 32;
            if (kk[i] != ~0ull) {
                bk[i] = key_bucket(kk[i]);
                atomicAdd(&hist[w * 32 + bk[i]], 1u);
            }
        }
        int hv = (l < 32) ? (int)hist[w * 32 + l] : 0; // atomics above are same-wave: ordered
        #pragma unroll
        for (int off = 1; off <= 16; off <<= 1) {   // inclusive scan, lanes 0..31
            int o = __shfl_up(hv, off);
            if (l >= off) hv += o;
        }
        u64 ge = __ballot((l < 32) && (hv >= KNBR));
        int B = __ffsll((unsigned long long)ge) - 1;        // threshold bucket
        int S = (B == 0) ? 0 : __shfl(hv, B - 1);           // count strictly below B
        #pragma unroll
        for (int i = 0; i < 7; i++) {                       // bulk-select below B
            if (kk[i] != ~0ull) {
                if (bk[i] < B) { int p = atomicAdd(&cnt2[w], 1); nbrl[w * 32 + p] = (int)(u32)kk[i]; }
                if (bk[i] != B) kk[i] = ~0ull;              // keep only bucket-B keys
            }
        }
        int need = KNBR - S;                                // expected ~4-12 rounds
        u64 last = 0;
        for (int r = 0; r < need; r++) {
            u64 mn = ~0ull;
            #pragma unroll
            for (int i = 0; i < 7; i++) if (kk[i] > last && kk[i] < mn) mn = kk[i];
            mn = wave_min_u64(mn);
            if (l == 0) nbrl[w * 32 + S + r] = (int)(u32)mn;
            last = mn;
        }
        if (l < KNBR) selj = nbrl[w * 32 + l];
    } else {
        // overflow fallback (never taken for uniform data): streaming 32-round argmin
        u64 last = 0;
        for (int r = 0; r < KNBR; r++) {
            u64 mn = ~0ull;
            for (int t = l; t < PCLOUD; t += 64) {
                int j = base + t;
                float px = pos[j * 3], py = pos[j * 3 + 1], pz = pos[j * 3 + 2];
                float sp = __fadd_rn(__fadd_rn(__fmul_rn(px, px), __fmul_rn(py, py)), __fmul_rn(pz, pz));
                float dt = __fadd_rn(__fadd_rn(__fmul_rn(cx, px), __fmul_rn(cy, py)), __fmul_rn(cz, pz));
                float d2 = __fsub_rn(__fadd_rn(sc, sp), __fmul_rn(2.0f, dt));
                if (d2 <= R2) { u64 kf = d2key(d2, j); if (kf > last && kf < mn) mn = kf; }
            }
            mn = wave_min_u64(mn);
            if (l == r) selj = (int)(u32)mn;
            last = mn;
        }
    }
    __syncthreads();   // lists/hist dead; smem becomes sA | sW dbuf

    uint4* sA4  = (uint4*)smem;
    uint4* sWb0 = (uint4*)(smem + 32768);
    uint4* sWb1 = (uint4*)(smem + 36864);

    uint4 ld = {};
    if constexpr (WS) ld = ws4[tid];                       // load step 0

    // ---- gather 32 feat rows per wave (XOR 16B-chunk swizzle); rows are wave-private ----
    {
        int h = l & 1, rl = l >> 1;
        int row = w * 32 + rl;
        int j = __shfl(selj, rl);
        int xv = row & 7;
        uint4* dst = sA4 + row * 16;
        uint4 z; z.x = z.y = z.z = z.w = 0;
        if (j >= 0) {
            const float4* sx = (const float4*)(x + (size_t)j * DIN);
            int c0lo = h ? 6 : 0, c0hi = h ? 8 : 6;
            for (int c0 = c0lo; c0 < c0hi; c0++) {
                float4 f0 = sx[c0 * 2], f1 = sx[c0 * 2 + 1];
                uint4 pv;
                pv.x = cvtpk(f0.x, f0.y); pv.y = cvtpk(f0.z, f0.w);
                pv.z = cvtpk(f1.x, f1.y); pv.w = cvtpk(f1.z, f1.w);
                dst[c0 ^ xv] = pv;
            }
            if (h == 1) {
                float rx = pos[j * 3] - cx, ry = pos[j * 3 + 1] - cy, rz = pos[j * 3 + 2] - cz;
                uint4 rc; rc.x = cvtpk(rx, ry); rc.y = cvtpk(rz, 0.0f); rc.z = 0; rc.w = 0;
                dst[8 ^ xv] = rc;
                dst[9 ^ xv] = z; dst[10 ^ xv] = z; dst[11 ^ xv] = z;
            }
        } else {
            int c0lo = h ? 6 : 0, c0hi = h ? 12 : 6;
            for (int c0 = c0lo; c0 < c0hi; c0++) dst[c0 ^ xv] = z;
        }
    }
    commitW<WS>(0, ld, sWb0, tid, W1, W2, W3);
    if constexpr (WS) ld = ws4[256 + tid];                 // load step 1
    __syncthreads();

    int m16 = l & 15, quad = l >> 4;
    int r0 = w * 32;
    const floatx4 vzero = {0.f, 0.f, 0.f, 0.f};

    // ======== GEMM1: h1 = relu(feat @ W1 + b1), K=96, swapped operands, 8 N-steps ========
    {
        bf16x8 a1[3][2];
        #pragma unroll
        for (int ki = 0; ki < 3; ki++)
            #pragma unroll
            for (int t = 0; t < 2; t++) {
                int row = r0 + t * 16 + m16;
                a1[ki][t] = __builtin_bit_cast(bf16x8, sA4[row * 16 + ((ki * 4 + quad) ^ (row & 7))]);
            }
        #pragma unroll 2
        for (int s = 0; s < 8; s++) {
            uint4* buf  = (s & 1) ? sWb1 : sWb0;
            uint4* nbuf = (s & 1) ? sWb0 : sWb1;
            floatx4 acc[2] = {vzero, vzero};
            #pragma unroll
            for (int ki = 0; ki < 3; ki++) {
                bf16x8 b = __builtin_bit_cast(bf16x8, buf[(m16 << 4) + ((ki * 4 + quad) ^ (m16 & 7))]);
                #pragma unroll
                for (int t = 0; t < 2; t++)
                    acc[t] = __builtin_amdgcn_mfma_f32_16x16x32_bf16(b, a1[ki][t], acc[t], 0, 0, 0);
            }
            float4 bb = ((const float4*)b1)[s * 4 + quad];  // cols s*16+quad*4..+3
            #pragma unroll
            for (int t = 0; t < 2; t++) {
                int rr = r0 + t * 16 + m16;
                uint2 pv;
                pv.x = cvtpk(fmaxf(acc[t][0] + bb.x, 0.f), fmaxf(acc[t][1] + bb.y, 0.f));
                pv.y = cvtpk(fmaxf(acc[t][2] + bb.z, 0.f), fmaxf(acc[t][3] + bb.w, 0.f));
                *(uint2*)(smem + rr * 256 + (((s * 2 + (quad >> 1)) ^ (rr & 7)) << 4) + ((quad & 1) << 3)) = pv;
            }
            commitW<WS>(s + 1, ld, nbuf, tid, W1, W2, W3);
            if constexpr (WS) ld = ws4[(s + 2) * 256 + tid];
            __syncthreads();
        }
    }

    // ======== GEMM2: h2 = relu(h1 @ W2 + b2), K=128, swapped operands, 8 N-steps ========
    {
        bf16x8 a2[4][2];
        #pragma unroll
        for (int ki = 0; ki < 4; ki++)
            #pragma unroll
            for (int t = 0; t < 2; t++) {
                int row = r0 + t * 16 + m16;
                a2[ki][t] = __builtin_bit_cast(bf16x8, sA4[row * 16 + ((ki * 4 + quad) ^ (row & 7))]);
            }
        #pragma unroll 2
        for (int s = 0; s < 8; s++) {
            uint4* buf  = (s & 1) ? sWb1 : sWb0;
            uint4* nbuf = (s & 1) ? sWb0 : sWb1;
            floatx4 acc[2] = {vzero, vzero};
            #pragma unroll
            for (int ki = 0; ki < 4; ki++) {
                bf16x8 b = __builtin_bit_cast(bf16x8, buf[(m16 << 4) + ((ki * 4 + quad) ^ (m16 & 7))]);
                #pragma unroll
                for (int t = 0; t < 2; t++)
                    acc[t] = __builtin_amdgcn_mfma_f32_16x16x32_bf16(b, a2[ki][t], acc[t], 0, 0, 0);
            }
            float4 bb = ((const float4*)b2)[s * 4 + quad];
            #pragma unroll
            for (int t = 0; t < 2; t++) {
                int rr = r0 + t * 16 + m16;
                uint2 pv;
                pv.x = cvtpk(fmaxf(acc[t][0] + bb.x, 0.f), fmaxf(acc[t][1] + bb.y, 0.f));
                pv.y = cvtpk(fmaxf(acc[t][2] + bb.z, 0.f), fmaxf(acc[t][3] + bb.w, 0.f));
                *(uint2*)(smem + rr * 256 + (((s * 2 + (quad >> 1)) ^ (rr & 7)) << 4) + ((quad & 1) << 3)) = pv;
            }
            commitW<WS>(s + 9, ld, nbuf, tid, W1, W2, W3);
            if constexpr (WS) ld = ws4[(s + 10) * 256 + tid];
            __syncthreads();
        }
    }

    // ==== GEMM3: out = maxpool(relu(h2 @ W3 + b3)), K=128, N=256, 16 N-steps ====
    {
        bf16x8 a3[4][2];
        #pragma unroll
        for (int ki = 0; ki < 4; ki++)
            #pragma unroll
            for (int t = 0; t < 2; t++) {
                int row = r0 + t * 16 + m16;
                a3[ki][t] = __builtin_bit_cast(bf16x8, sA4[row * 16 + ((ki * 4 + quad) ^ (row & 7))]);
            }
        #pragma unroll 2
        for (int s = 0; s < 16; s++) {
            uint4* buf  = (s & 1) ? sWb1 : sWb0;
            uint4* nbuf = (s & 1) ? sWb0 : sWb1;
            floatx4 acc[2] = {vzero, vzero};
            #pragma unroll
            for (int ki = 0; ki < 4; ki++) {
                bf16x8 b = __builtin_bit_cast(bf16x8, buf[(m16 << 4) + ((ki * 4 + quad) ^ (m16 & 7))]);
                #pragma unroll
                for (int t = 0; t < 2; t++)
                    acc[t] = __builtin_amdgcn_mfma_f32_16x16x32_bf16(a3[ki][t], b, acc[t], 0, 0, 0);
            }
            int col = s * 16 + m16;
            float bias = b3[col];
            float mv = 0.0f;   // post-ReLU max over >=1 valid nbr is >= 0
            #pragma unroll
            for (int t = 0; t < 2; t++)
                #pragma unroll
                for (int i = 0; i < 4; i++) {
                    int k = t * 16 + quad * 4 + i;
                    float v = fmaxf(acc[t][i] + bias, 0.0f);
                    if (k < nsel) mv = fmaxf(mv, v);
                }
            mv = fmaxf(mv, __shfl_xor(mv, 16));
            mv = fmaxf(mv, __shfl_xor(mv, 32));
            if (quad == 0) out[(m0 + w) * 256 + col] = mv;
            if (s < 15) {
                commitW<WS>(s + 17, ld, nbuf, tid, W1, W2, W3);
                if constexpr (WS) { if (s < 14) ld = ws4[(s + 18) * 256 + tid]; }
                __syncthreads();
            }
        }
    }
}

extern "C" void kernel_launch(void* const* d_in, const int* in_sizes, int n_in,
                              void* d_out, int out_size, void* d_ws, size_t ws_size,
                              hipStream_t stream) {
    const float* x     = (const float*)d_in[0];
    const float* pos   = (const float*)d_in[1];
    const int*   batch = (const int*)d_in[2];
    const int*   idx   = (const int*)d_in[3];
    const float* W1    = (const float*)d_in[4];
    const float* b1    = (const float*)d_in[5];
    const float* W2    = (const float*)d_in[6];
    const float* b2    = (const float*)d_in[7];
    const float* W3    = (const float*)d_in[8];
    const float* b3    = (const float*)d_in[9];
    float* out = (float*)d_out;
    uint4* ws4 = (uint4*)d_ws;

    if (ws_size >= 131072) {
        hipLaunchKernelGGL(prep_kernel, dim3(32), dim3(256), 0, stream, W1, W2, W3, ws4);
        hipLaunchKernelGGL((sa_kernel<true>), dim3(MCENT / 4), dim3(256), 0, stream,
                           x, pos, batch, idx, W1, b1, W2, b2, W3, b3, ws4, out);
    } else {
        hipLaunchKernelGGL((sa_kernel<false>), dim3(MCENT / 4), dim3(256), 0, stream,
                           x, pos, batch, idx, W1, b1, W2, b2, W3, b3, ws4, out);
    }
}